// Round 14
// baseline (34.456 us; speedup 1.0000x reference)
//
#include <hip/hip_runtime.h>
#include <math.h>

// PROBE ROUND: round-10 structure EXACTLY (prefetch reverted -- round 13
// showed it regresses), with the pooling+reduce wrapped in 8 in-kernel reps
// (bin origin opaqued per rep via asm, rule #17) so the dispatch exceeds the
// ~40us harness fills and appears in rocprof top-5 WITH counters.
// Diagnosis tree: Occupancy<25% -> concurrency-limited; VALUBusy>40% ->
// instruction-bound; else per-rep vs BW math -> at floor, declare ceiling.
//
// Structure: 4 waves per bin (256-thread block), round-robin row split
// (wave W takes rows W, W+4, W+8; R<=3), exact unpadded inline-asm load
// batches (<=15 loads, ONE s_waitcnt vmcnt(0) + sched_barrier(0) each),
// LDS max-combine, wave 0 writes. XCD swizzle: block p -> bin
// (p&7)*588+(p>>3).

#define NB 2
#define NR 48
#define FH 56
#define FW 56
#define PH 7
#define PW 7
#define NBINS (NB * NR * PH * PW)   // 4704 blocks = 8 XCD groups * 588
#define REPS 8

__device__ inline void fm4max(float4& m, const float4 v) {
  m.x = fmaxf(m.x, v.x);
  m.y = fmaxf(m.y, v.y);
  m.z = fmaxf(m.z, v.z);
  m.w = fmaxf(m.w, v.w);
}

__device__ inline float4 gload(const float4* p) {
  float4 v;
  asm volatile("global_load_dwordx4 %0, %1, off" : "=v"(v) : "v"(p));
  return v;
}

// Exact RxK pixel batch: rows row0 + 4k (k<R), cols c0..c0+K-1.
template <int R, int K>
__device__ inline float4 pool_part(const float4* __restrict__ base,
                                   int row0, int c0) {
  float4 v[R][K];
#pragma unroll
  for (int k = 0; k < R; ++k) {
    const float4* rowp =
        base + (size_t)(row0 + 4 * k) * (FW * 64) + (size_t)c0 * 64;
#pragma unroll
    for (int q = 0; q < K; ++q) v[k][q] = gload(rowp + (size_t)q * 64);
  }
  asm volatile("s_waitcnt vmcnt(0)" ::: "memory");
  __builtin_amdgcn_sched_barrier(0);
  float4 m0 = v[0][0], m1 = v[0][1];            // K >= 2 always
#pragma unroll
  for (int k = 0; k < R; ++k)
#pragma unroll
    for (int q = 0; q < K; ++q) {
      if (k == 0 && q < 2) continue;
      if (((k * K + q) & 1) == 0) fm4max(m0, v[k][q]);
      else                        fm4max(m1, v[k][q]);
    }
  fm4max(m0, m1);
  return m0;
}

// This wave's R rows x full bin width Ew (wave-uniform switch; Ew in [2,10]).
template <int R>
__device__ inline float4 pool_R(const float4* __restrict__ base,
                                int r0w, int c0, int Ew) {
  switch (Ew) {
    case 2: return pool_part<R, 2>(base, r0w, c0);
    case 3: return pool_part<R, 3>(base, r0w, c0);
    case 4: return pool_part<R, 4>(base, r0w, c0);
    case 5: return pool_part<R, 5>(base, r0w, c0);
    case 6: { float4 a = pool_part<R, 3>(base, r0w, c0);
              float4 b = pool_part<R, 3>(base, r0w, c0 + 3);
              fm4max(a, b); return a; }
    case 7: { float4 a = pool_part<R, 4>(base, r0w, c0);
              float4 b = pool_part<R, 3>(base, r0w, c0 + 4);
              fm4max(a, b); return a; }
    case 8: { float4 a = pool_part<R, 4>(base, r0w, c0);
              float4 b = pool_part<R, 4>(base, r0w, c0 + 4);
              fm4max(a, b); return a; }
    case 9: { float4 a = pool_part<R, 5>(base, r0w, c0);
              float4 b = pool_part<R, 4>(base, r0w, c0 + 5);
              fm4max(a, b); return a; }
    default:{ float4 a = pool_part<R, 5>(base, r0w, c0);
              float4 b = pool_part<R, 5>(base, r0w, c0 + 5);
              fm4max(a, b); return a; }
  }
}

__global__ __launch_bounds__(256) void roi_pool_kernel(
    const float4* __restrict__ fm4, const float* __restrict__ rois,
    float4* __restrict__ out4) {
  const int lane = threadIdx.x & 63;          // channel group (4 ch each)
  const int wv = threadIdx.x >> 6;            // 0..3: row-split wave id
  const int p = blockIdx.x;

  // XCD swizzle: contiguous 588-bin slab per XCD (img0 on XCDs 0-3).
  int bin = (p & 7) * (NBINS / 8) + (p >> 3);
  const int obin = bin;

  const int j = bin % PW; bin /= PW;
  const int i = bin % PH; bin /= PH;
  const int r = bin % NR;
  const int b = bin / NR;

  const float* roi = rois + (b * NR + r) * 4;
  const float x = roi[0], y = roi[1], w = roi[2], h = roi[3];

  // Match JAX reference fp32 arithmetic + trunc-to-int32 exactly.
  const int w_start = (int)(56.0f * x);
  const int w_end   = (int)(56.0f * (x + w));
  const int h_start = (int)(56.0f * (1.0f - y));
  const int h_end   = (int)(56.0f * (1.0f - y + h));
  const int rh = h_end - h_start;
  const int rw = w_end - w_start;
  const int h_step = rh / PH;
  const int w_step = rw / PW;

  const int r0 = h_start + i * h_step;
  const int r1 = (i == PH - 1) ? (h_start + rh) : (r0 + h_step);
  const int c0 = w_start + j * w_step;
  const int c1 = (j == PW - 1) ? (w_start + rw) : (c0 + w_step);

  const int Eh = r1 - r0;                     // in [2, 10]
  const int Ew = c1 - c0;                     // in [2, 10]

  // Round-robin rows: wave wv owns rows r0+wv, r0+wv+4, r0+wv+8 (< r1).
  const int R = (Eh - wv + 3) >> 2;           // 0..3 rows for this wave

  const float4* base = fm4 + ((size_t)(b * FH) * FW) * 64 + lane;

  __shared__ float4 red[4][64];

  for (int rep = 0; rep < REPS; ++rep) {
    int r0v = r0 + wv, c0v = c0;
    // Opaque: compiler can't prove reps identical -> all 8 bodies stay live.
    asm volatile("" : "+v"(r0v), "+v"(c0v));

    float4 m = make_float4(-INFINITY, -INFINITY, -INFINITY, -INFINITY);
    if (R == 1)      m = pool_R<1>(base, r0v, c0v, Ew);
    else if (R == 2) m = pool_R<2>(base, r0v, c0v, Ew);
    else if (R == 3) m = pool_R<3>(base, r0v, c0v, Ew);

    red[wv][lane] = m;
    __syncthreads();
    if (wv == 0) {
      fm4max(m, red[1][lane]);
      fm4max(m, red[2][lane]);
      fm4max(m, red[3][lane]);
      out4[(size_t)obin * 64 + lane] = m;
    }
    __syncthreads();                          // WAR: red reused next rep
  }
}

extern "C" void kernel_launch(void* const* d_in, const int* in_sizes, int n_in,
                              void* d_out, int out_size, void* d_ws, size_t ws_size,
                              hipStream_t stream) {
  const float4* fm4 = (const float4*)d_in[0];
  const float* rois = (const float*)d_in[1];
  float4* out4 = (float4*)d_out;
  roi_pool_kernel<<<NBINS, 256, 0, stream>>>(fm4, rois, out4);
}

// Round 15
// 11.487 us; speedup vs baseline: 2.9995x; 2.9995x over previous
//
#include <hip/hip_runtime.h>
#include <math.h>

// RoI pooling: fm [2,56,56,256] f32, rois [2,48,4] f32 (x, y_max, w, h),
// out [2,48,7,7,256] f32.
//
// Structure (round 10 = best known, 11.1us): 4 waves per bin (256-thread
// block), round-robin row split (wave W takes rows W, W+4, W+8; R<=3),
// exact unpadded inline-asm load batches (<=15 loads, ONE s_waitcnt
// vmcnt(0) + sched_barrier(0) each; rule #18), LDS max-combine, wave 0
// writes. XCD swizzle: block p -> bin (p&7)*588+(p>>3); image 0 on XCDs
// 0-3, image 1 on 4-7.
//
// Round-14 probe decomposition: 11.1 = 3.8 replay floor + 3.3 warm compute
// (L2-served) + 4.0 cold pull. Cold pull is HBM-BW-SATURATED at ~25 MB
// (4 XCDs x each pulls its whole 6.4/2=3.2MB image, ~4x duplication) --
// only lever is TRAFFIC REDUCTION.
//
// Round 15: DISJOINT-QUARTER prefetch. XCD x prefetches only bytes
// [q*784KB,(q+1)*784KB) of its image (q = x&3): one 1KB slot for each of
// the first 784 waves in the XCD group. Chip-wide prefetch = exactly
// 6.4 MB, no overlap (vs round 13's 2.5x-redundant full-image prefetch
// which regressed). The quarters land in L3; each XCD's demand misses for
// the other 3/4 then hit L3 instead of HBM: cold HBM traffic ~25 -> ~10 MB.
// Hazards (learned rounds 11-13): dest reg pinned live via component-wise
// asm sink after an explicit vmcnt(0) drain (nothing outstanding at
// s_endpgm); prefetch condition is wave-uniform.

#define NB 2
#define NR 48
#define FH 56
#define FW 56
#define PH 7
#define PW 7
#define NBINS (NB * NR * PH * PW)   // 4704 blocks = 8 XCD groups * 588
#define IMG_BYTES (FH * FW * 256 * 4)        // 3211264 B per image
#define QTR_SLOTS 784                        // 1KB slots per image quarter

__device__ inline void fm4max(float4& m, const float4 v) {
  m.x = fmaxf(m.x, v.x);
  m.y = fmaxf(m.y, v.y);
  m.z = fmaxf(m.z, v.z);
  m.w = fmaxf(m.w, v.w);
}

__device__ inline float4 gload(const float4* p) {
  float4 v;
  asm volatile("global_load_dwordx4 %0, %1, off" : "=v"(v) : "v"(p));
  return v;
}

// Exact RxK pixel batch: rows row0 + 4k (k<R), cols c0..c0+K-1.
// All R*K loads issued back-to-back (<=15), ONE wait, fmax tree.
template <int R, int K>
__device__ inline float4 pool_part(const float4* __restrict__ base,
                                   int row0, int c0) {
  float4 v[R][K];
#pragma unroll
  for (int k = 0; k < R; ++k) {
    const float4* rowp =
        base + (size_t)(row0 + 4 * k) * (FW * 64) + (size_t)c0 * 64;
#pragma unroll
    for (int q = 0; q < K; ++q) v[k][q] = gload(rowp + (size_t)q * 64);
  }
  asm volatile("s_waitcnt vmcnt(0)" ::: "memory");
  __builtin_amdgcn_sched_barrier(0);
  float4 m0 = v[0][0], m1 = v[0][1];            // K >= 2 always
#pragma unroll
  for (int k = 0; k < R; ++k)
#pragma unroll
    for (int q = 0; q < K; ++q) {
      if (k == 0 && q < 2) continue;
      if (((k * K + q) & 1) == 0) fm4max(m0, v[k][q]);
      else                        fm4max(m1, v[k][q]);
    }
  fm4max(m0, m1);
  return m0;
}

// This wave's R rows x full bin width Ew (wave-uniform switch; Ew in [2,10]).
// Ew<=5: one batch/one wait. Ew>=6: two exact batches (no padding).
template <int R>
__device__ inline float4 pool_R(const float4* __restrict__ base,
                                int r0w, int c0, int Ew) {
  switch (Ew) {
    case 2: return pool_part<R, 2>(base, r0w, c0);
    case 3: return pool_part<R, 3>(base, r0w, c0);
    case 4: return pool_part<R, 4>(base, r0w, c0);
    case 5: return pool_part<R, 5>(base, r0w, c0);
    case 6: { float4 a = pool_part<R, 3>(base, r0w, c0);
              float4 b = pool_part<R, 3>(base, r0w, c0 + 3);
              fm4max(a, b); return a; }
    case 7: { float4 a = pool_part<R, 4>(base, r0w, c0);
              float4 b = pool_part<R, 3>(base, r0w, c0 + 4);
              fm4max(a, b); return a; }
    case 8: { float4 a = pool_part<R, 4>(base, r0w, c0);
              float4 b = pool_part<R, 4>(base, r0w, c0 + 4);
              fm4max(a, b); return a; }
    case 9: { float4 a = pool_part<R, 5>(base, r0w, c0);
              float4 b = pool_part<R, 4>(base, r0w, c0 + 5);
              fm4max(a, b); return a; }
    default:{ float4 a = pool_part<R, 5>(base, r0w, c0);
              float4 b = pool_part<R, 5>(base, r0w, c0 + 5);
              fm4max(a, b); return a; }
  }
}

__global__ __launch_bounds__(256) void roi_pool_kernel(
    const float4* __restrict__ fm4, const float* __restrict__ rois,
    float4* __restrict__ out4) {
  const int lane = threadIdx.x & 63;          // channel group (4 ch each)
  const int wv = threadIdx.x >> 6;            // 0..3: row-split wave id
  const int p = blockIdx.x;

  // --- Disjoint-quarter L3 prefetch (one 1KB slot per early wave).
  float4 pf0 = make_float4(0.f, 0.f, 0.f, 0.f);
  const int xcd = p & 7;
  const int g = p >> 3;                       // 0..587 within XCD group
  const int widx = g * 4 + wv;                // wave idx within XCD group
  if (widx < QTR_SLOTS) {                     // wave-uniform condition
    const int img = xcd >> 2;                 // XCDs 0-3 -> img0, 4-7 -> img1
    const int qtr = xcd & 3;                  // quarter owned by this XCD
    const char* pa = (const char*)fm4 + (size_t)img * IMG_BYTES +
                     (size_t)qtr * (QTR_SLOTS * 1024) +
                     (size_t)widx * 1024 + (size_t)lane * 16;
    asm volatile("global_load_dwordx4 %0, %1, off" : "=&v"(pf0) : "v"(pa));
  }

  // XCD swizzle: contiguous 588-bin slab per XCD (img0 on XCDs 0-3).
  int bin = xcd * (NBINS / 8) + g;
  const int obin = bin;

  const int j = bin % PW; bin /= PW;
  const int i = bin % PH; bin /= PH;
  const int r = bin % NR;
  const int b = bin / NR;

  const float* roi = rois + (b * NR + r) * 4;
  const float x = roi[0], y = roi[1], w = roi[2], h = roi[3];

  // Match JAX reference fp32 arithmetic + trunc-to-int32 exactly.
  const int w_start = (int)(56.0f * x);
  const int w_end   = (int)(56.0f * (x + w));
  const int h_start = (int)(56.0f * (1.0f - y));
  const int h_end   = (int)(56.0f * (1.0f - y + h));
  const int rh = h_end - h_start;
  const int rw = w_end - w_start;
  const int h_step = rh / PH;
  const int w_step = rw / PW;

  const int r0 = h_start + i * h_step;
  const int r1 = (i == PH - 1) ? (h_start + rh) : (r0 + h_step);
  const int c0 = w_start + j * w_step;
  const int c1 = (j == PW - 1) ? (w_start + rw) : (c0 + w_step);

  const int Eh = r1 - r0;                     // in [2, 10]
  const int Ew = c1 - c0;                     // in [2, 10]

  // Round-robin rows: wave wv owns rows r0+wv, r0+wv+4, r0+wv+8 (< r1).
  const int R = (Eh - wv + 3) >> 2;           // 0..3 rows for this wave

  const float4* base = fm4 + ((size_t)(b * FH) * FW) * 64 + lane;

  float4 m = make_float4(-INFINITY, -INFINITY, -INFINITY, -INFINITY);
  if (R == 1)      m = pool_R<1>(base, r0 + wv, c0, Ew);
  else if (R == 2) m = pool_R<2>(base, r0 + wv, c0, Ew);
  else if (R == 3) m = pool_R<3>(base, r0 + wv, c0, Ew);

  // Drain + sink: nothing outstanding at endpgm; pf reg pinned until here.
  asm volatile("s_waitcnt vmcnt(0)" ::: "memory");
  asm volatile("" :: "v"(pf0.x), "v"(pf0.y), "v"(pf0.z), "v"(pf0.w));

  __shared__ float4 red[4][64];
  red[wv][lane] = m;
  __syncthreads();
  if (wv == 0) {
    fm4max(m, red[1][lane]);
    fm4max(m, red[2][lane]);
    fm4max(m, red[3][lane]);
    out4[(size_t)obin * 64 + lane] = m;
  }
}

extern "C" void kernel_launch(void* const* d_in, const int* in_sizes, int n_in,
                              void* d_out, int out_size, void* d_ws, size_t ws_size,
                              hipStream_t stream) {
  const float4* fm4 = (const float4*)d_in[0];
  const float* rois = (const float*)d_in[1];
  float4* out4 = (float4*)d_out;
  roi_pool_kernel<<<NBINS, 256, 0, stream>>>(fm4, rois, out4);
}

// Round 16
// 11.082 us; speedup vs baseline: 3.1092x; 1.0366x over previous
//
#include <hip/hip_runtime.h>
#include <math.h>

// RoI pooling: fm [2,56,56,256] f32, rois [2,48,4] f32 (x, y_max, w, h),
// out [2,48,7,7,256] f32.  FINAL: best-known structure (round 10, 11.1us).
//
// Structure: 4 waves per bin (256-thread block), round-robin row split
// (wave W takes rows W, W+4, W+8; R<=3), exact unpadded inline-asm load
// batches (<=15 loads, ONE s_waitcnt vmcnt(0) + sched_barrier(0) each --
// the compiler otherwise register-minimizes into serial load->wait->fmax
// chains, round-7 probe), LDS max-combine, wave 0 writes. XCD swizzle:
// block p -> bin (p&7)*588+(p>>3); image 0 on XCDs 0-3, image 1 on 4-7.
//
// Measured decomposition (probes rounds 4/7/14): 11.1us = 3.8 replay floor
// + ~4.0 cold HBM pull (21-25 MB at 6.3 TB/s, BW-saturated; 4x duplication
// forced by runtime ROI->XCD assignment) + ~3.3 warm L2 compute (66 MB
// exact reads, algorithmic minimum). Prefetch variants (rounds 13/15) both
// null/regress: cold traffic irreducible from kernel source.

#define NB 2
#define NR 48
#define FH 56
#define FW 56
#define PH 7
#define PW 7
#define NBINS (NB * NR * PH * PW)   // 4704 blocks = 8 XCD groups * 588

__device__ inline void fm4max(float4& m, const float4 v) {
  m.x = fmaxf(m.x, v.x);
  m.y = fmaxf(m.y, v.y);
  m.z = fmaxf(m.z, v.z);
  m.w = fmaxf(m.w, v.w);
}

__device__ inline float4 gload(const float4* p) {
  float4 v;
  asm volatile("global_load_dwordx4 %0, %1, off" : "=v"(v) : "v"(p));
  return v;
}

// Exact RxK pixel batch: rows row0 + 4k (k<R), cols c0..c0+K-1.
// All R*K loads issued back-to-back (<=15), ONE wait, fmax tree.
template <int R, int K>
__device__ inline float4 pool_part(const float4* __restrict__ base,
                                   int row0, int c0) {
  float4 v[R][K];
#pragma unroll
  for (int k = 0; k < R; ++k) {
    const float4* rowp =
        base + (size_t)(row0 + 4 * k) * (FW * 64) + (size_t)c0 * 64;
#pragma unroll
    for (int q = 0; q < K; ++q) v[k][q] = gload(rowp + (size_t)q * 64);
  }
  asm volatile("s_waitcnt vmcnt(0)" ::: "memory");
  __builtin_amdgcn_sched_barrier(0);
  float4 m0 = v[0][0], m1 = v[0][1];            // K >= 2 always
#pragma unroll
  for (int k = 0; k < R; ++k)
#pragma unroll
    for (int q = 0; q < K; ++q) {
      if (k == 0 && q < 2) continue;
      if (((k * K + q) & 1) == 0) fm4max(m0, v[k][q]);
      else                        fm4max(m1, v[k][q]);
    }
  fm4max(m0, m1);
  return m0;
}

// This wave's R rows x full bin width Ew (wave-uniform switch; Ew in [2,10]).
// Ew<=5: one batch/one wait. Ew>=6: two exact batches (no padding).
template <int R>
__device__ inline float4 pool_R(const float4* __restrict__ base,
                                int r0w, int c0, int Ew) {
  switch (Ew) {
    case 2: return pool_part<R, 2>(base, r0w, c0);
    case 3: return pool_part<R, 3>(base, r0w, c0);
    case 4: return pool_part<R, 4>(base, r0w, c0);
    case 5: return pool_part<R, 5>(base, r0w, c0);
    case 6: { float4 a = pool_part<R, 3>(base, r0w, c0);
              float4 b = pool_part<R, 3>(base, r0w, c0 + 3);
              fm4max(a, b); return a; }
    case 7: { float4 a = pool_part<R, 4>(base, r0w, c0);
              float4 b = pool_part<R, 3>(base, r0w, c0 + 4);
              fm4max(a, b); return a; }
    case 8: { float4 a = pool_part<R, 4>(base, r0w, c0);
              float4 b = pool_part<R, 4>(base, r0w, c0 + 4);
              fm4max(a, b); return a; }
    case 9: { float4 a = pool_part<R, 5>(base, r0w, c0);
              float4 b = pool_part<R, 4>(base, r0w, c0 + 5);
              fm4max(a, b); return a; }
    default:{ float4 a = pool_part<R, 5>(base, r0w, c0);
              float4 b = pool_part<R, 5>(base, r0w, c0 + 5);
              fm4max(a, b); return a; }
  }
}

__global__ __launch_bounds__(256) void roi_pool_kernel(
    const float4* __restrict__ fm4, const float* __restrict__ rois,
    float4* __restrict__ out4) {
  const int lane = threadIdx.x & 63;          // channel group (4 ch each)
  const int wv = threadIdx.x >> 6;            // 0..3: row-split wave id
  const int p = blockIdx.x;

  // XCD swizzle: contiguous 588-bin slab per XCD (img0 on XCDs 0-3).
  int bin = (p & 7) * (NBINS / 8) + (p >> 3);
  const int obin = bin;

  const int j = bin % PW; bin /= PW;
  const int i = bin % PH; bin /= PH;
  const int r = bin % NR;
  const int b = bin / NR;

  const float* roi = rois + (b * NR + r) * 4;
  const float x = roi[0], y = roi[1], w = roi[2], h = roi[3];

  // Match JAX reference fp32 arithmetic + trunc-to-int32 exactly.
  const int w_start = (int)(56.0f * x);
  const int w_end   = (int)(56.0f * (x + w));
  const int h_start = (int)(56.0f * (1.0f - y));
  const int h_end   = (int)(56.0f * (1.0f - y + h));
  const int rh = h_end - h_start;
  const int rw = w_end - w_start;
  const int h_step = rh / PH;
  const int w_step = rw / PW;

  const int r0 = h_start + i * h_step;
  const int r1 = (i == PH - 1) ? (h_start + rh) : (r0 + h_step);
  const int c0 = w_start + j * w_step;
  const int c1 = (j == PW - 1) ? (w_start + rw) : (c0 + w_step);

  const int Eh = r1 - r0;                     // in [2, 10]
  const int Ew = c1 - c0;                     // in [2, 10]

  // Round-robin rows: wave wv owns rows r0+wv, r0+wv+4, r0+wv+8 (< r1).
  const int R = (Eh - wv + 3) >> 2;           // 0..3 rows for this wave

  const float4* base = fm4 + ((size_t)(b * FH) * FW) * 64 + lane;

  float4 m = make_float4(-INFINITY, -INFINITY, -INFINITY, -INFINITY);
  if (R == 1)      m = pool_R<1>(base, r0 + wv, c0, Ew);
  else if (R == 2) m = pool_R<2>(base, r0 + wv, c0, Ew);
  else if (R == 3) m = pool_R<3>(base, r0 + wv, c0, Ew);

  __shared__ float4 red[4][64];
  red[wv][lane] = m;
  __syncthreads();
  if (wv == 0) {
    fm4max(m, red[1][lane]);
    fm4max(m, red[2][lane]);
    fm4max(m, red[3][lane]);
    out4[(size_t)obin * 64 + lane] = m;
  }
}

extern "C" void kernel_launch(void* const* d_in, const int* in_sizes, int n_in,
                              void* d_out, int out_size, void* d_ws, size_t ws_size,
                              hipStream_t stream) {
  const float4* fm4 = (const float4*)d_in[0];
  const float* rois = (const float*)d_in[1];
  float4* out4 = (float4*)d_out;
  roi_pool_kernel<<<NBINS, 256, 0, stream>>>(fm4, rois, out4);
}